// Round 18
// baseline (45.169 us; speedup 1.0000x reference)
//
#include <hip/hip_runtime.h>

#define N_ROWS   1024
#define D_DIM    128
#define C_CLS    50000
#define C_PAD    50048
#define NCT64    782        // 50048/64 column tiles (64 cols each)
#define NG       128        // ct groups; 782 = 6*128 + 14
#define NPART    256        // partials per row = NG * 2 col-halves
#define S_SCALE  30.0f
#define M_MARGIN 0.35f
#define EXP2_SCALE 43.2808512266689f    // 30 * log2(e)  (folded into fhat)
#define EXP2M      15.1482979293341f    // M_MARGIN * EXP2_SCALE
#define LN2        0.6931471805599453f

typedef short s8v __attribute__((ext_vector_type(8)));   // 8 x bf16 bits (4 VGPRs)
typedef float f4v __attribute__((ext_vector_type(4)));

__device__ inline unsigned short f2bf(float f) {
    unsigned u = __float_as_uint(f);
    u += 0x7FFF + ((u >> 16) & 1);      // round-to-nearest-even (inputs are finite)
    return (unsigned short)(u >> 16);
}
__device__ inline float bf2f(unsigned short h) {
    return __uint_as_float(((unsigned)h) << 16);
}
__device__ inline void load_lds16(const char* src, unsigned char* lds) {
    __builtin_amdgcn_global_load_lds(
        (const __attribute__((address_space(1))) void*)src,
        (__attribute__((address_space(3))) void*)lds, 16, 0, 0);
}

// ---------------------------------------------------------------------------
// Row-normalize with XCD-MATCHED placement for weight rows (r15, kept).
// float4 loads, 2 rows/wave. fhat norm scaled by EXP2_SCALE.
// ---------------------------------------------------------------------------
__global__ void norm_rows_fused(const float* __restrict__ weight,
                                const float* __restrict__ feature,
                                unsigned short* __restrict__ what,
                                unsigned short* __restrict__ fhat) {
    int wid = threadIdx.x >> 6, lane = threadIdx.x & 63;
    int half = lane >> 5, l32 = lane & 31;
    int B = blockIdx.x;

    const float* src;
    unsigned short* dst;
    int rowBase, isW;
    float scale;
    if (B < 6272) {                       // weight rows, XCD-matched
        int x = B & 7, q = B >> 3;
        int ct = x + 8 * (q >> 3);
        if (ct >= NCT64) return;          // idle tail
        rowBase = ct * 64 + (q & 7) * 8;
        src = weight; dst = what; scale = 1.0f; isW = 1;
    } else {                              // feature rows, natural
        rowBase = (B - 6272) * 8;
        src = feature; dst = fhat; scale = EXP2_SCALE; isW = 0;
    }

    int srcRow = rowBase + wid * 2 + half;
    int valid = isW ? (srcRow < C_CLS) : 1;

    float4 v = make_float4(0.f, 0.f, 0.f, 0.f);
    if (valid) v = ((const float4*)src)[(size_t)srcRow * 32 + l32];
    float ss = v.x * v.x + v.y * v.y + v.z * v.z + v.w * v.w;
    #pragma unroll
    for (int s = 1; s < 32; s <<= 1) ss += __shfl_xor(ss, s, 32);
    float inv = valid ? scale / fmaxf(sqrtf(ss), 1e-8f) : 0.f;
    ushort4 o;
    o.x = f2bf(v.x * inv); o.y = f2bf(v.y * inv);
    o.z = f2bf(v.z * inv); o.w = f2bf(v.w * inv);
    ((ushort4*)dst)[(size_t)srcRow * 32 + l32] = o;
}

// ---------------------------------------------------------------------------
// Helpers for the deferred-exp pipeline (all static indexing, rule #20).
// ---------------------------------------------------------------------------
__device__ __forceinline__ void stage4(const char* src, unsigned char* dstb,
                                       int wid, int lane) {
    #pragma unroll
    for (int ii = 0; ii < 4; ii++) {
        int o = wid * 4096 + ii * 1024 + lane * 16;
        int s = o ^ (((o >> 8) & 7) << 4);   // XOR swizzle on GLOBAL src (rule #21)
        load_lds16(src + s, dstb + o);
    }
}

__device__ __forceinline__ void mfma_tile(const unsigned char* bb, const int (&vb)[2][4],
                                          const s8v (&afr)[4][4], f4v (&acc)[4][2]) {
    const f4v FZERO = {0.f, 0.f, 0.f, 0.f};
    {   // kk = 0: C = FZERO (no acc zero-init movs)
        s8v b0 = *(const s8v*)(bb + vb[0][0]);
        s8v b1 = *(const s8v*)(bb + vb[1][0]);
        #pragma unroll
        for (int m = 0; m < 4; m++) {
            acc[m][0] = __builtin_amdgcn_mfma_f32_16x16x32_bf16(afr[0][m], b0, FZERO, 0, 0, 0);
            acc[m][1] = __builtin_amdgcn_mfma_f32_16x16x32_bf16(afr[0][m], b1, FZERO, 0, 0, 0);
        }
    }
    #pragma unroll
    for (int kk = 1; kk < 4; kk++) {
        s8v b0 = *(const s8v*)(bb + vb[0][kk]);
        s8v b1 = *(const s8v*)(bb + vb[1][kk]);
        #pragma unroll
        for (int m = 0; m < 4; m++) {
            acc[m][0] = __builtin_amdgcn_mfma_f32_16x16x32_bf16(afr[kk][m], b0, acc[m][0], 0, 0, 0);
            acc[m][1] = __builtin_amdgcn_mfma_f32_16x16x32_bf16(afr[kk][m], b1, acc[m][1], 0, 0, 0);
        }
    }
}

__device__ __forceinline__ void exp_acc(const f4v (&acc)[4][2], float (&esum)[4][4]) {
    #pragma unroll
    for (int m = 0; m < 4; m++)
        #pragma unroll
        for (int n = 0; n < 2; n++)
            #pragma unroll
            for (int j = 0; j < 4; j++)
                esum[m][j] += __builtin_amdgcn_exp2f(acc[m][n][j]);
}

__device__ __forceinline__ void exp_acc_masked(const f4v (&acc)[4][2], float (&esum)[4][4],
                                               int ct, int wcol, int lrow) {
    #pragma unroll
    for (int n = 0; n < 2; n++) {
        int gc = ct * 64 + wcol * 32 + n * 16 + lrow;
        #pragma unroll
        for (int m = 0; m < 4; m++)
            #pragma unroll
            for (int j = 0; j < 4; j++)
                if (gc < C_CLS)
                    esum[m][j] += __builtin_amdgcn_exp2f(acc[m][n][j]);
    }
}

// ---------------------------------------------------------------------------
// ct-loop GEMM+exp, DEFERRED-EXP double pipeline (T15 applied to r15 base).
// Iteration i: barrier -> stage(i+1) -> MFMA tile i into p[cur] -> exp-
// accumulate p[prev] (tile i-1). The exp ops are INDEPENDENT of the in-
// flight MFMAs -> one wave dual-feeds the TRANS and MFMA pipes, removing the
// per-tile MFMA->exp serial chain (r17 falsified the TLP route; this is the
// ILP route). Two named acc sets pA/pB, even/odd body duplication (rule #20).
// Tail masking only in the epilogue (in-loop exps are provably full tiles:
// exp at iter i covers ct = g+128*(i-1) <= g+128*(nt-2) < 781).
// Everything else == r15 (verified 35.3us): 2x16KB B dbuf, __syncthreads per
// tile, XOR swizzle on GLOBAL source, linear LDS dest, hoisted vb[2][4].
// Register cost +32 (pB) -> ~148 total -> 3 waves/SIMD (occupancy measured-
// insensitive r5-r13). SESSION RULE: never >=4 waves/EU (r10/r12 spills).
// ---------------------------------------------------------------------------
__global__ __launch_bounds__(256, 3)
void gemm_exp_kernel(const short* __restrict__ fhat,
                     const short* __restrict__ what,
                     float* __restrict__ part2) {
    __shared__ __align__(16) unsigned char smem[32768];   // 2 x 16KB B buffers
    const int g   = blockIdx.x;           // ct group, 0..127
    const int rt  = blockIdx.y;           // row tile, 0..7
    const int tid = threadIdx.x;
    const int wid = tid >> 6;
    const int lane = tid & 63;
    const int lrow = lane & 15;
    const int kgrp = lane >> 4;
    const int wrow = wid >> 1;            // row half (64 rows)
    const int wcol = wid & 1;             // col half (32 cols)
    const int nt = (g < 14) ? 7 : 6;      // tiles in this group (782 = 6*128+14)

    const char* aSrc  = (const char*)fhat + (size_t)rt * 32768;
    const char* bBase = (const char*)what;

    // ---- prologue: A tile (32KB) -> whole smem, then A -> registers ----
    #pragma unroll
    for (int i = 0; i < 8; i++) {
        int o = wid * 8192 + i * 1024 + lane * 16;
        int s = o ^ (((o >> 8) & 7) << 4);      // source pre-swizzle (involution)
        load_lds16(aSrc + s, smem + o);
    }
    __syncthreads();

    s8v afr[4][4];                        // wave rows: wrow*64 + m*16 + lrow
    #pragma unroll
    for (int kk = 0; kk < 4; kk++)
        #pragma unroll
        for (int m = 0; m < 4; m++) {
            int row = wrow * 64 + m * 16 + lrow;
            int b = (row * 256 + kk * 64 + kgrp * 16) ^ ((row & 7) << 4);
            afr[kk][m] = *(const s8v*)(smem + b);
        }
    __syncthreads();                      // afr reads retired; smem reusable

    // ---- loop-invariant B ds_read addresses ----
    int vb[2][4];
    #pragma unroll
    for (int n = 0; n < 2; n++)
        #pragma unroll
        for (int kk = 0; kk < 4; kk++) {
            int row = wcol * 32 + n * 16 + lrow;   // B^T row = output col
            vb[n][kk] = (row * 256 + kk * 64 + kgrp * 16) ^ ((row & 7) << 4);
        }

    // ---- stage B(t=0) -> buf0 ----
    stage4(bBase + (size_t)g * 16384, smem, wid, lane);

    float esum[4][4];
    #pragma unroll
    for (int m = 0; m < 4; m++)
        #pragma unroll
        for (int j = 0; j < 4; j++) esum[m][j] = 0.f;

    f4v pA[4][2], pB[4][2];               // two named acc sets (static idx)

    // ---- iteration 0 -> pA (no deferred exp yet) ----
    __syncthreads();
    if (nt > 1) stage4(bBase + (size_t)(g + 128) * 16384, smem + 16384, wid, lane);
    mfma_tile(smem, vb, afr, pA);

    int i = 1;
    while (i < nt) {
        // odd iteration -> pB, exp(pA = tile i-1)
        __syncthreads();
        if (i + 1 < nt)
            stage4(bBase + (size_t)(g + 128 * (i + 1)) * 16384, smem, wid, lane);
        mfma_tile(smem + 16384, vb, afr, pB);
        exp_acc(pA, esum);
        ++i;
        if (i >= nt) break;
        // even iteration -> pA, exp(pB = tile i-1)
        __syncthreads();
        if (i + 1 < nt)
            stage4(bBase + (size_t)(g + 128 * (i + 1)) * 16384, smem + 16384, wid, lane);
        mfma_tile(smem, vb, afr, pA);
        exp_acc(pB, esum);
        ++i;
    }

    // ---- epilogue exp of the final tile (the only maskable one) ----
    const int ctLast = g + 128 * (nt - 1);
    if (nt & 1) {                         // last iteration index nt-1 even -> pA
        if (ctLast != NCT64 - 1) exp_acc(pA, esum);
        else                     exp_acc_masked(pA, esum, ctLast, wcol, lrow);
    } else {                              // -> pB
        if (ctLast != NCT64 - 1) exp_acc(pB, esum);
        else                     exp_acc_masked(pB, esum, ctLast, wcol, lrow);
    }

    // ---- epilogue: reduce over the wave's 16 col-lanes, direct write ----
    #pragma unroll
    for (int m = 0; m < 4; m++)
        #pragma unroll
        for (int j = 0; j < 4; j++) {
            float v = esum[m][j];
            v += __shfl_xor(v, 1, 64);
            v += __shfl_xor(v, 2, 64);
            v += __shfl_xor(v, 4, 64);
            v += __shfl_xor(v, 8, 64);
            if (lrow == 0) {
                int row = rt * 128 + wrow * 64 + m * 16 + kgrp * 4 + j;
                part2[(size_t)row * NPART + g * 2 + wcol] = v;
            }
        }
}

// ---------------------------------------------------------------------------
// One wave per row: S_n = sum of 256 partials (4 per lane). cys = fp32 dot of
// the SAME bf16 vectors = EXP2_SCALE*cos_y, so Sp = S - exp2(cys) +
// exp2(cys - EXP2M); rowval[n] = (ln(Sp) - LN2*t2)/N + 0.005*||f_n - w_y||^2
// ---------------------------------------------------------------------------
__global__ void finalize_rows_kernel(const float* __restrict__ part2,
                                     const unsigned short* __restrict__ fhat,
                                     const unsigned short* __restrict__ what,
                                     const float* __restrict__ feature,
                                     const float* __restrict__ weight,
                                     const int* __restrict__ label,
                                     float* __restrict__ rowval) {
    int wid = threadIdx.x >> 6, lane = threadIdx.x & 63;
    int n = blockIdx.x * 4 + wid;
    int y = label[n];

    const float* p = part2 + (size_t)n * NPART;
    float S = p[lane] + p[64 + lane] + p[128 + lane] + p[192 + lane];

    float2 f2 = ((const float2*)feature)[(size_t)n * 64 + lane];
    float2 w2 = ((const float2*)weight)[(size_t)y * 64 + lane];
    float dx = f2.x - w2.x, dy = f2.y - w2.y;
    float cl = dx * dx + dy * dy;

    ushort2 fh = ((const ushort2*)fhat)[(size_t)n * 64 + lane];
    ushort2 wh = ((const ushort2*)what)[(size_t)y * 64 + lane];
    float cys = bf2f(fh.x) * bf2f(wh.x) + bf2f(fh.y) * bf2f(wh.y);

    #pragma unroll
    for (int s = 1; s < 64; s <<= 1) {
        S   += __shfl_xor(S, s, 64);
        cl  += __shfl_xor(cl, s, 64);
        cys += __shfl_xor(cys, s, 64);
    }
    if (lane == 0) {
        float t2 = cys - EXP2M;
        float Sp = S - __builtin_amdgcn_exp2f(cys) + __builtin_amdgcn_exp2f(t2);
        rowval[n] = (logf(Sp) - LN2 * t2) * (1.0f / (float)N_ROWS) + 0.005f * cl;
    }
}

__global__ void reduce_final_kernel(const float* __restrict__ rowval, float* __restrict__ out) {
    __shared__ float sbuf[4];
    int t = threadIdx.x;
    float v = rowval[t] + rowval[t + 256] + rowval[t + 512] + rowval[t + 768];
    #pragma unroll
    for (int s = 1; s < 64; s <<= 1) v += __shfl_xor(v, s, 64);
    if ((t & 63) == 0) sbuf[t >> 6] = v;
    __syncthreads();
    if (t == 0) out[0] = sbuf[0] + sbuf[1] + sbuf[2] + sbuf[3];
}

// ---------------------------------------------------------------------------
extern "C" void kernel_launch(void* const* d_in, const int* in_sizes, int n_in,
                              void* d_out, int out_size, void* d_ws, size_t ws_size,
                              hipStream_t stream) {
    const float* feature = (const float*)d_in[0];
    const float* weight  = (const float*)d_in[1];
    const int*   label   = (const int*)d_in[2];

    // Workspace layout (bytes):
    //   what   [0,        12812288)  : 50048*128*2
    //   fhat   [12812288, 13074432)  : 1024*128*2
    //   part2  [13074432, 14123008)  : 1024*256*4
    //   rowval [14123008, 14127104)  : 1024*4
    const size_t WS_NEEDED = 14127104;
    if (ws_size < WS_NEEDED) return;   // defensive: visible failure, not OOB writes

    char* ws = (char*)d_ws;
    unsigned short* what = (unsigned short*)ws;
    unsigned short* fhat = (unsigned short*)(ws + 12812288);
    float*         part2 = (float*)(ws + 13074432);
    float*        rowval = (float*)(ws + 14123008);

    norm_rows_fused<<<dim3(6400), 256, 0, stream>>>(weight, feature, what, fhat);
    gemm_exp_kernel<<<dim3(NG, 8), 256, 0, stream>>>((const short*)fhat, (const short*)what, part2);
    finalize_rows_kernel<<<dim3(N_ROWS / 4), 256, 0, stream>>>(part2, fhat, what, feature, weight,
                                                               label, rowval);
    reduce_final_kernel<<<1, 256, 0, stream>>>(rowval, (float*)d_out);
}

// Round 19
// 35.170 us; speedup vs baseline: 1.2843x; 1.2843x over previous
//
#include <hip/hip_runtime.h>

#define N_ROWS   1024
#define D_DIM    128
#define C_CLS    50000
#define C_PAD    50048
#define NCT64    782        // 50048/64 column tiles (64 cols each)
#define NG       128        // ct groups; 782 = 6*128 + 14
#define NPART    256        // partials per row = NG * 2 col-halves
#define S_SCALE  30.0f
#define M_MARGIN 0.35f
#define EXP2_SCALE 43.2808512266689f    // 30 * log2(e)  (folded into fhat)
#define EXP2M      15.1482979293341f    // M_MARGIN * EXP2_SCALE
#define LN2        0.6931471805599453f

typedef short s8v __attribute__((ext_vector_type(8)));   // 8 x bf16 bits (4 VGPRs)
typedef float f4v __attribute__((ext_vector_type(4)));

__device__ inline unsigned short f2bf(float f) {
    unsigned u = __float_as_uint(f);
    u += 0x7FFF + ((u >> 16) & 1);      // round-to-nearest-even (inputs are finite)
    return (unsigned short)(u >> 16);
}
__device__ inline float bf2f(unsigned short h) {
    return __uint_as_float(((unsigned)h) << 16);
}
__device__ inline void load_lds16(const char* src, unsigned char* lds) {
    __builtin_amdgcn_global_load_lds(
        (const __attribute__((address_space(1))) void*)src,
        (__attribute__((address_space(3))) void*)lds, 16, 0, 0);
}

// ---------------------------------------------------------------------------
// Row-normalize with XCD-MATCHED placement for weight rows.
// The 8 norm blocks writing B tile ct run on XCD ct%8 = the XCD whose gemm
// blocks read it -> tile lands in the reader's L2. float4 loads, 2 rows/wave.
// fhat norm scaled by EXP2_SCALE (GEMM output directly in exp2 units).
// ---------------------------------------------------------------------------
__global__ void norm_rows_fused(const float* __restrict__ weight,
                                const float* __restrict__ feature,
                                unsigned short* __restrict__ what,
                                unsigned short* __restrict__ fhat) {
    int wid = threadIdx.x >> 6, lane = threadIdx.x & 63;
    int half = lane >> 5, l32 = lane & 31;
    int B = blockIdx.x;

    const float* src;
    unsigned short* dst;
    int rowBase, isW;
    float scale;
    if (B < 6272) {                       // weight rows, XCD-matched
        int x = B & 7, q = B >> 3;
        int ct = x + 8 * (q >> 3);
        if (ct >= NCT64) return;          // idle tail (x in {6,7}, c2 == 97)
        rowBase = ct * 64 + (q & 7) * 8;
        src = weight; dst = what; scale = 1.0f; isW = 1;
    } else {                              // feature rows, natural
        rowBase = (B - 6272) * 8;
        src = feature; dst = fhat; scale = EXP2_SCALE; isW = 0;
    }

    int srcRow = rowBase + wid * 2 + half;
    int valid = isW ? (srcRow < C_CLS) : 1;

    float4 v = make_float4(0.f, 0.f, 0.f, 0.f);
    if (valid) v = ((const float4*)src)[(size_t)srcRow * 32 + l32];
    float ss = v.x * v.x + v.y * v.y + v.z * v.z + v.w * v.w;
    #pragma unroll
    for (int s = 1; s < 32; s <<= 1) ss += __shfl_xor(ss, s, 32);
    float inv = valid ? scale / fmaxf(sqrtf(ss), 1e-8f) : 0.f;
    ushort4 o;
    o.x = f2bf(v.x * inv); o.y = f2bf(v.y * inv);
    o.z = f2bf(v.z * inv); o.w = f2bf(v.w * inv);
    ((ushort4*)dst)[(size_t)srcRow * 32 + l32] = o;
}

// ---------------------------------------------------------------------------
// ct-loop GEMM+exp (round-15, best measured: total 35.3us — restored after
// r16 inf / r17 neutral-rotation / r18 T15-regression bisects).
// Block (g, rt): 128 rows x 64 cols per tile, tiles ct = g + 128*t (6-7).
// LDS 32KB: A bounces through it in the prologue -> registers; then TWO
// 16KB B buffers. Per tile: __syncthreads() -> issue stage(t+1) -> compute.
// XOR swizzle on the GLOBAL source (rule #21), linear LDS dest.
//  (1) zero-C trick: first k-step uses FZERO as MFMA C (no acc-init movs).
//  (2) B ds_read addresses hoisted to vb[2][4] (loop-invariant).
// SESSION RULE: never request >=4 waves/EU (r10/r12: allocator clamps to 64
// VGPR and spills 45-49MB scratch). (256,3) = ~84 VGPR spill-free; HW still
// resides 4 blocks/CU since 84+acc <= 128-step and LDS 32KB allows 5.
// ---------------------------------------------------------------------------
__global__ __launch_bounds__(256, 3)
void gemm_exp_kernel(const short* __restrict__ fhat,
                     const short* __restrict__ what,
                     float* __restrict__ part2) {
    __shared__ __align__(16) unsigned char smem[32768];   // 2 x 16KB B buffers
    const int g   = blockIdx.x;           // ct group, 0..127
    const int rt  = blockIdx.y;           // row tile, 0..7
    const int tid = threadIdx.x;
    const int wid = tid >> 6;
    const int lane = tid & 63;
    const int lrow = lane & 15;
    const int kgrp = lane >> 4;
    const int wrow = wid >> 1;            // row half (64 rows)
    const int wcol = wid & 1;             // col half (32 cols)
    const int nt = (g < 14) ? 7 : 6;      // tiles in this group (782 = 6*128+14)

    const char* aSrc  = (const char*)fhat + (size_t)rt * 32768;
    const char* bBase = (const char*)what;

    // ---- prologue: A tile (32KB) -> whole smem, then A -> registers ----
    #pragma unroll
    for (int i = 0; i < 8; i++) {
        int o = wid * 8192 + i * 1024 + lane * 16;
        int s = o ^ (((o >> 8) & 7) << 4);      // source pre-swizzle (involution)
        load_lds16(aSrc + s, smem + o);
    }
    __syncthreads();

    s8v afr[4][4];                        // wave rows: wrow*64 + m*16 + lrow
    #pragma unroll
    for (int kk = 0; kk < 4; kk++)
        #pragma unroll
        for (int m = 0; m < 4; m++) {
            int row = wrow * 64 + m * 16 + lrow;
            int b = (row * 256 + kk * 64 + kgrp * 16) ^ ((row & 7) << 4);
            afr[kk][m] = *(const s8v*)(smem + b);
        }
    __syncthreads();                      // afr reads retired; smem reusable

    // ---- loop-invariant B ds_read addresses ----
    int vb[2][4];
    #pragma unroll
    for (int n = 0; n < 2; n++)
        #pragma unroll
        for (int kk = 0; kk < 4; kk++) {
            int row = wcol * 32 + n * 16 + lrow;   // B^T row = output col
            vb[n][kk] = (row * 256 + kk * 64 + kgrp * 16) ^ ((row & 7) << 4);
        }

    // ---- stage B(t=0) -> buf0 ----
    #pragma unroll
    for (int i = 0; i < 4; i++) {
        int o = wid * 4096 + i * 1024 + lane * 16;
        int s = o ^ (((o >> 8) & 7) << 4);
        load_lds16(bBase + (size_t)g * 16384 + s, smem + o);
    }

    float esum[4][4];
    #pragma unroll
    for (int m = 0; m < 4; m++)
        #pragma unroll
        for (int j = 0; j < 4; j++) esum[m][j] = 0.f;

    const f4v FZERO = {0.f, 0.f, 0.f, 0.f};

    for (int t = 0; t < nt; ++t) {
        const int ct = g + 128 * t;
        // vmcnt(0)+lgkmcnt(0)+barrier: stage(t) landed; buf[(t+1)&1]'s
        // readers (tile t-1) all done -> safe to overwrite.
        __syncthreads();

        if (t + 1 < nt) {                 // issue stage(t+1) BEFORE compute
            const char* src = bBase + (size_t)(ct + 128) * 16384;
            unsigned char* dstb = smem + ((t + 1) & 1) * 16384;
            #pragma unroll
            for (int i = 0; i < 4; i++) {
                int o = wid * 4096 + i * 1024 + lane * 16;
                int s = o ^ (((o >> 8) & 7) << 4);
                load_lds16(src + s, dstb + o);
            }
        }

        const unsigned char* bb = smem + (t & 1) * 16384;
        f4v acc[4][2];

        {   // kk = 0: C = FZERO, no acc zero-init movs
            s8v b0 = *(const s8v*)(bb + vb[0][0]);
            s8v b1 = *(const s8v*)(bb + vb[1][0]);
            #pragma unroll
            for (int m = 0; m < 4; m++) {
                acc[m][0] = __builtin_amdgcn_mfma_f32_16x16x32_bf16(
                    afr[0][m], b0, FZERO, 0, 0, 0);
                acc[m][1] = __builtin_amdgcn_mfma_f32_16x16x32_bf16(
                    afr[0][m], b1, FZERO, 0, 0, 0);
            }
        }
        #pragma unroll
        for (int kk = 1; kk < 4; kk++) {
            s8v b0 = *(const s8v*)(bb + vb[0][kk]);
            s8v b1 = *(const s8v*)(bb + vb[1][kk]);
            #pragma unroll
            for (int m = 0; m < 4; m++) {
                acc[m][0] = __builtin_amdgcn_mfma_f32_16x16x32_bf16(
                    afr[kk][m], b0, acc[m][0], 0, 0, 0);
                acc[m][1] = __builtin_amdgcn_mfma_f32_16x16x32_bf16(
                    afr[kk][m], b1, acc[m][1], 0, 0, 0);
            }
        }

        if (ct != NCT64 - 1) {            // fast path: all 32 cols valid
            #pragma unroll
            for (int m = 0; m < 4; m++)
                #pragma unroll
                for (int n = 0; n < 2; n++)
                    #pragma unroll
                    for (int j = 0; j < 4; j++)
                        esum[m][j] += __builtin_amdgcn_exp2f(acc[m][n][j]);
        } else {                          // tail tile: mask padded cols
            #pragma unroll
            for (int n = 0; n < 2; n++) {
                int gc = ct * 64 + wcol * 32 + n * 16 + lrow;
                #pragma unroll
                for (int m = 0; m < 4; m++)
                    #pragma unroll
                    for (int j = 0; j < 4; j++)
                        if (gc < C_CLS)
                            esum[m][j] += __builtin_amdgcn_exp2f(acc[m][n][j]);
            }
        }
    }

    // ---- epilogue: reduce over the wave's 16 col-lanes, direct write ----
    #pragma unroll
    for (int m = 0; m < 4; m++)
        #pragma unroll
        for (int j = 0; j < 4; j++) {
            float v = esum[m][j];
            v += __shfl_xor(v, 1, 64);
            v += __shfl_xor(v, 2, 64);
            v += __shfl_xor(v, 4, 64);
            v += __shfl_xor(v, 8, 64);
            if (lrow == 0) {
                int row = rt * 128 + wrow * 64 + m * 16 + kgrp * 4 + j;
                part2[(size_t)row * NPART + g * 2 + wcol] = v;
            }
        }
}

// ---------------------------------------------------------------------------
// One wave per row: S_n = sum of 256 partials (4 per lane). cys = fp32 dot of
// the SAME bf16 vectors = EXP2_SCALE*cos_y, so Sp = S - exp2(cys) +
// exp2(cys - EXP2M); rowval[n] = (ln(Sp) - LN2*t2)/N + 0.005*||f_n - w_y||^2
// ---------------------------------------------------------------------------
__global__ void finalize_rows_kernel(const float* __restrict__ part2,
                                     const unsigned short* __restrict__ fhat,
                                     const unsigned short* __restrict__ what,
                                     const float* __restrict__ feature,
                                     const float* __restrict__ weight,
                                     const int* __restrict__ label,
                                     float* __restrict__ rowval) {
    int wid = threadIdx.x >> 6, lane = threadIdx.x & 63;
    int n = blockIdx.x * 4 + wid;
    int y = label[n];

    const float* p = part2 + (size_t)n * NPART;
    float S = p[lane] + p[64 + lane] + p[128 + lane] + p[192 + lane];

    float2 f2 = ((const float2*)feature)[(size_t)n * 64 + lane];
    float2 w2 = ((const float2*)weight)[(size_t)y * 64 + lane];
    float dx = f2.x - w2.x, dy = f2.y - w2.y;
    float cl = dx * dx + dy * dy;

    ushort2 fh = ((const ushort2*)fhat)[(size_t)n * 64 + lane];
    ushort2 wh = ((const ushort2*)what)[(size_t)y * 64 + lane];
    float cys = bf2f(fh.x) * bf2f(wh.x) + bf2f(fh.y) * bf2f(wh.y);

    #pragma unroll
    for (int s = 1; s < 64; s <<= 1) {
        S   += __shfl_xor(S, s, 64);
        cl  += __shfl_xor(cl, s, 64);
        cys += __shfl_xor(cys, s, 64);
    }
    if (lane == 0) {
        float t2 = cys - EXP2M;
        float Sp = S - __builtin_amdgcn_exp2f(cys) + __builtin_amdgcn_exp2f(t2);
        rowval[n] = (logf(Sp) - LN2 * t2) * (1.0f / (float)N_ROWS) + 0.005f * cl;
    }
}

__global__ void reduce_final_kernel(const float* __restrict__ rowval, float* __restrict__ out) {
    __shared__ float sbuf[4];
    int t = threadIdx.x;
    float v = rowval[t] + rowval[t + 256] + rowval[t + 512] + rowval[t + 768];
    #pragma unroll
    for (int s = 1; s < 64; s <<= 1) v += __shfl_xor(v, s, 64);
    if ((t & 63) == 0) sbuf[t >> 6] = v;
    __syncthreads();
    if (t == 0) out[0] = sbuf[0] + sbuf[1] + sbuf[2] + sbuf[3];
}

// ---------------------------------------------------------------------------
extern "C" void kernel_launch(void* const* d_in, const int* in_sizes, int n_in,
                              void* d_out, int out_size, void* d_ws, size_t ws_size,
                              hipStream_t stream) {
    const float* feature = (const float*)d_in[0];
    const float* weight  = (const float*)d_in[1];
    const int*   label   = (const int*)d_in[2];

    // Workspace layout (bytes):
    //   what   [0,        12812288)  : 50048*128*2
    //   fhat   [12812288, 13074432)  : 1024*128*2
    //   part2  [13074432, 14123008)  : 1024*256*4
    //   rowval [14123008, 14127104)  : 1024*4
    const size_t WS_NEEDED = 14127104;
    if (ws_size < WS_NEEDED) return;   // defensive: visible failure, not OOB writes

    char* ws = (char*)d_ws;
    unsigned short* what = (unsigned short*)ws;
    unsigned short* fhat = (unsigned short*)(ws + 12812288);
    float*         part2 = (float*)(ws + 13074432);
    float*        rowval = (float*)(ws + 14123008);

    norm_rows_fused<<<dim3(6400), 256, 0, stream>>>(weight, feature, what, fhat);
    gemm_exp_kernel<<<dim3(NG, 8), 256, 0, stream>>>((const short*)fhat, (const short*)what, part2);
    finalize_rows_kernel<<<dim3(N_ROWS / 4), 256, 0, stream>>>(part2, fhat, what, feature, weight,
                                                               label, rowval);
    reduce_final_kernel<<<1, 256, 0, stream>>>(rowval, (float*)d_out);
}